// Round 15
// baseline (116.409 us; speedup 1.0000x reference)
//
#include <hip/hip_runtime.h>
#include <hip/hip_bf16.h>

#define BB 8
#define NN 8192
#define MM 2048
#define C1 64
#define C2 128
#define CIN 192
#define CO 128
#define NB (BB*NN)
#define EPS 1e-5f

#define PRE_ARGMIN 2048
#define PRE_PREPH  (PRE_ARGMIN + 512)
#define PRE_TOTAL  (PRE_PREPH + 96)

typedef unsigned short u16;
typedef unsigned int u32;
typedef __bf16 bf16_t;
typedef bf16_t bf16x8 __attribute__((ext_vector_type(8)));
typedef float f32x4 __attribute__((ext_vector_type(4)));
typedef float f32x2 __attribute__((ext_vector_type(2)));

static __device__ __forceinline__ float b2f(u16 u) { return __uint_as_float(((u32)u) << 16); }
static __device__ __forceinline__ u16 f2b(float f) {
    __hip_bfloat16 h = __float2bfloat16(f);
    u16 u; __builtin_memcpy(&u, &h, 2); return u;
}

// ================= k_pre: argmin (b128 + pk-f32) + hT transpose + weight convert =================
__global__ __launch_bounds__(256) void k_pre(
        const float* __restrict__ lt_, const float* __restrict__ lp_,
        const float* __restrict__ ht_, const float* __restrict__ hp_,
        const float* __restrict__ hf, const float* __restrict__ W0, const float* __restrict__ W1,
        int* __restrict__ idx, u16* __restrict__ hT,
        u16* __restrict__ W0b, u16* __restrict__ W1b) {
    __shared__ float2 hs[8 * 260];                  // 16.6KB; reused as u16[64][65] by prep_h
    int bid = blockIdx.x, tid = threadIdx.x;

    if (bid < PRE_ARGMIN) {
        // ---- nearest neighbor: branchless exact scan (R14 b128 + R11 pk-f32 d2) ----
        // d2 = (x-lt)^2 + (y-lp)^2 via v_pk_add/mul + scalar rn-add; bitwise == np's
        // mul,mul,add on (lt-x, lp-y) [negation & add-commutativity exact in IEEE rn].
        // Per chain keep LAST hit (strictly-decreasing d2) AND PREV hit; sqrt-tie
        // promotes prev (earlier index) == np.argmin over sqrt, first-index ties.
        int b = bid >> 8;                           // 256 blocks per batch
        int n0 = (bid & 255) << 5;                  // 32 queries per block
        for (int e = tid; e < MM; e += 256) {
            int p = e >> 8, i = e & 255;
            hs[p * 260 + i] = make_float2(ht_[b * MM + e], hp_[b * MM + e]);
        }
        __syncthreads();
        int q = tid >> 3, p = tid & 7;              // 32 queries x 8 m-parts per block
        float lt = lt_[b * NN + n0 + q];
        float lp = lp_[b * NN + n0 + q];
        f32x2 nq; nq[0] = -lt; nq[1] = -lp;
        float dl[4] = {1e30f, 1e30f, 1e30f, 1e30f};
        float dpv[4] = {1e30f, 1e30f, 1e30f, 1e30f};
        int il[4] = {0, 0, 0, 0}, ipx[4] = {0, 0, 0, 0};   // local indices 0..255
        const float2* hp2 = &hs[p * 260];
#pragma unroll 8
        for (int k = 0; k < 64; ++k) {              // 4 cands/iter via 2x ds_read_b128
            f32x4 v0 = *(const f32x4*)&hp2[k * 4];  // {x0,y0,x1,y1}
            f32x4 v1 = *(const f32x4*)&hp2[k * 4 + 2];  // {x2,y2,x3,y3}
            f32x2 pc[4];
            pc[0][0] = v0[0]; pc[0][1] = v0[1];
            pc[1][0] = v0[2]; pc[1][1] = v0[3];
            pc[2][0] = v1[0]; pc[2][1] = v1[1];
            pc[3][0] = v1[2]; pc[3][1] = v1[3];
            float d2v[4];
#pragma unroll
            for (int c = 0; c < 4; ++c) {
                f32x2 e;
                asm("v_pk_add_f32 %0, %1, %2" : "=v"(e) : "v"(pc[c]), "v"(nq));
                asm("v_pk_mul_f32 %0, %1, %2" : "=v"(e) : "v"(e), "v"(e));
                d2v[c] = __fadd_rn(e[0], e[1]);     // rn add == np's fadd
            }
#pragma unroll
            for (int c = 0; c < 4; ++c) {           // chain c: cands 4k+c (ascending)
                bool hit = d2v[c] < dl[c];          // strict <
                dpv[c] = hit ? dl[c] : dpv[c];
                ipx[c] = hit ? il[c] : ipx[c];
                dl[c]  = hit ? d2v[c] : dl[c];
                il[c]  = hit ? (k * 4 + c) : il[c];
            }
        }
        int mbase = p << 8;
        float bs = 1e30f; int bm = 0x7fffffff;
#pragma unroll
        for (int c = 0; c < 4; ++c) {
            float sl = __fsqrt_rn(dl[c]);
            float sp = __fsqrt_rn(dpv[c]);
            int cand = mbase + ((sp == sl) ? ipx[c] : il[c]);  // sqrt-tie -> earlier hit
            if (sl < bs || (sl == bs && cand < bm)) { bs = sl; bm = cand; }
        }
#pragma unroll
        for (int d = 1; d <= 4; d <<= 1) {          // merge 8 parts (lanes 8q+p)
            float ov = __shfl_xor(bs, d, 64);
            int om = __shfl_xor(bm, d, 64);
            if (ov < bs || (ov == bs && om < bm)) { bs = ov; bm = om; }
        }
        if (p == 0) idx[b * NN + n0 + q] = bm;
    } else if (bid < PRE_PREPH) {
        // ---- high_feats transpose: f32 [B][C2][M] -> bf16 [B][M][C2] ----
        u16 (*s)[65] = (u16(*)[65])hs;
        int bid2 = bid - PRE_ARGMIN;
        int b = bid2 >> 6, m0 = ((bid2 >> 1) & 31) * 64, c0 = (bid2 & 1) * 64;
        for (int e = tid; e < 64 * 64; e += 256) {
            int i = e >> 6, j = e & 63;             // i: c, j: m (coalesced in m)
            s[i][j] = f2b(hf[(b * C2 + c0 + i) * MM + m0 + j]);
        }
        __syncthreads();
        for (int e = tid; e < 64 * 64; e += 256) {
            int ii = e & 63, jj = e >> 6;           // coalesced in c
            hT[(b * MM + m0 + jj) * C2 + c0 + ii] = s[ii][jj];
        }
    } else {
        // ---- weights f32 -> bf16 ----
        int t = (bid - PRE_PREPH) * 256 + tid;
        if (t < CIN * CO) W0b[t] = f2b(W0[t]);
        if (t < CO * CO)  W1b[t] = f2b(W1[t]);
    }
}

// epilogue: bias add, per-channel sum/sumsq into LDS chs/chq, bf16 store to ylds
static __device__ __forceinline__ void epilogue(
        f32x4* ac0, f32x4* ac1, const float* bias, u16* yl,
        float* chs, float* chq, int w, int ln, int q) {
#pragma unroll
    for (int mf = 0; mf < 2; ++mf) {
        f32x4* A = mf ? ac1 : ac0;
        int chb = 32 * w + 16 * mf + 4 * q;
        float bs[4], ss[4] = {0.f, 0.f, 0.f, 0.f}, sq[4] = {0.f, 0.f, 0.f, 0.f};
#pragma unroll
        for (int r = 0; r < 4; ++r) bs[r] = bias[chb + r];
#pragma unroll
        for (int nf = 0; nf < 4; ++nf) {
            int n = (nf << 4) + ln;
#pragma unroll
            for (int r = 0; r < 4; ++r) {
                float y = A[nf][r] + bs[r];
                ss[r] += y; sq[r] += y * y;
                int o = chb + r;
                yl[(o << 6) + (n ^ ((o & 7) << 3))] = f2b(y);
            }
        }
#pragma unroll
        for (int r = 0; r < 4; ++r) {
            float v = ss[r], u2 = sq[r];
#pragma unroll
            for (int d = 1; d < 16; d <<= 1) {
                v += __shfl_xor(v, d, 64);
                u2 += __shfl_xor(u2, d, 64);
            }
            if (ln == 0) { atomicAdd(&chs[chb + r], v); atomicAdd(&chq[chb + r], u2); }
        }
    }
}

// ---------------- deterministic stat reduce: gpart[1024][256] -> gout[256] ----------------
__global__ __launch_bounds__(256) void k_red(const float* __restrict__ gpart,
                                             float* __restrict__ gout) {
    __shared__ float part[4];
    int c = blockIdx.x;
    int t = threadIdx.x;
    float s = 0.f;
#pragma unroll
    for (int k = 0; k < 4; ++k)
        s += gpart[(t + (k << 8)) * 256 + c];
#pragma unroll
    for (int d = 1; d < 64; d <<= 1)
        s += __shfl_xor(s, d, 64);
    if ((t & 63) == 0) part[t >> 6] = s;
    __syncthreads();
    if (t == 0) gout[c] = (part[0] + part[1]) + (part[2] + part[3]);
}

// ---------------- layer 0: gather + MFMA gemm + bias -> y0 (ws, bf16) + stat partials ----------------
__global__ __launch_bounds__(256) void k_l0(
        const float* __restrict__ lf, const u16* __restrict__ hT, const int* __restrict__ idx,
        const u16* __restrict__ W0b, const float* __restrict__ b0,
        u16* __restrict__ y0, float* __restrict__ gpart) {
    __shared__ u16 xt[64 * CIN];          // B-tile [n][k] XOR-chunk-swizzled (24.5KB)
    __shared__ u16 ylds[CO * 64];         // y tile [o][n swz] (16KB)
    __shared__ float chs[CO], chq[CO];
    __shared__ int idxs[64];
    int tid = threadIdx.x;
    int l = tid & 63, w = tid >> 6, ln = l & 15, q = l >> 4;
    int b = blockIdx.x >> 7, n0 = (blockIdx.x & 127) << 6;
    if (tid < 64) idxs[tid] = idx[b * NN + n0 + tid];
    if (tid < 128) { chs[tid] = 0.f; chq[tid] = 0.f; }
    __syncthreads();
    // stage low_feats rows 0..63 via in-register transpose (lane = channel, f32 -> bf16)
    {
        const float* src = lf + (size_t)(b * C1 + l) * NN + n0 + (w << 4);
        float4 f0 = *(const float4*)src;
        float4 f1 = *(const float4*)(src + 4);
        float4 f2 = *(const float4*)(src + 8);
        float4 f3 = *(const float4*)(src + 12);
        float v[16] = {f0.x, f0.y, f0.z, f0.w, f1.x, f1.y, f1.z, f1.w,
                       f2.x, f2.y, f2.z, f2.w, f3.x, f3.y, f3.z, f3.w};
        int cc = l >> 3, clo = l & 7;
#pragma unroll
        for (int i = 0; i < 16; ++i) {
            int n = (w << 4) + i;
            xt[n * CIN + ((cc ^ (i & 7)) << 3) + clo] = f2b(v[i]);
        }
    }
    // gather nearest high rows (contiguous 256B per row from bf16 hT)
    for (int e = tid; e < 1024; e += 256) {
        int n = e >> 4, c16 = e & 15;
        uint4 v = *(const uint4*)(hT + (size_t)(b * MM + idxs[n]) * C2 + (c16 << 3));
        *(uint4*)&xt[n * CIN + (((8 + c16) ^ (n & 7)) << 3)] = v;
    }
    __syncthreads();
    f32x4 ac0[4], ac1[4];
#pragma unroll
    for (int nf = 0; nf < 4; ++nf) {
        ac0[nf] = f32x4{0.f, 0.f, 0.f, 0.f};
        ac1[nf] = f32x4{0.f, 0.f, 0.f, 0.f};
    }
    const u16* w0r0 = W0b + (32 * w + ln) * CIN + 8 * q;
    const u16* w0r1 = w0r0 + 16 * CIN;
#pragma unroll
    for (int s = 0; s < 6; ++s) {
        bf16x8 a0 = *(const bf16x8*)(w0r0 + 32 * s);
        bf16x8 a1 = *(const bf16x8*)(w0r1 + 32 * s);
#pragma unroll
        for (int nf = 0; nf < 4; ++nf) {
            bf16x8 bv = *(const bf16x8*)&xt[(16 * nf + ln) * CIN + (((4 * s + q) ^ (ln & 7)) << 3)];
            ac0[nf] = __builtin_amdgcn_mfma_f32_16x16x32_bf16(a0, bv, ac0[nf], 0, 0, 0);
            ac1[nf] = __builtin_amdgcn_mfma_f32_16x16x32_bf16(a1, bv, ac1[nf], 0, 0, 0);
        }
    }
    epilogue(ac0, ac1, b0, ylds, chs, chq, w, ln, q);
    __syncthreads();
    gpart[blockIdx.x * 256 + tid] = (tid < 128) ? chs[tid] : chq[tid - 128];
    // coalesced store ylds -> y0 (ws, bf16)
    {
        int o = tid >> 1, h = tid & 1;
#pragma unroll
        for (int jj = 0; jj < 4; ++jj) {
            int j = (h << 2) + jj;
            uint4 v = *(const uint4*)&ylds[(o << 6) + ((j ^ (o & 7)) << 3)];
            *(uint4*)(y0 + (size_t)(b * CO + o) * NN + n0 + (j << 3)) = v;
        }
    }
}

// ---------------- layer 1: BN0+ReLU on y0 tile -> MFMA gemm -> y1pre in place + stat partials ----------------
__global__ __launch_bounds__(256) void k_l1(
        u16* __restrict__ y, const float* __restrict__ g0, const float* __restrict__ be0,
        const u16* __restrict__ W1b, const float* __restrict__ b1,
        const float* __restrict__ gstat, float* __restrict__ gpart) {
    __shared__ u16 xt[64 * CO];           // B-tile [n][k] swz (16KB)
    __shared__ u16 ylds[CO * 64];         // (16KB)
    __shared__ float chs[CO], chq[CO], sc[CO], sh[CO];
    int tid = threadIdx.x;
    int l = tid & 63, w = tid >> 6, ln = l & 15, q = l >> 4;
    int b = blockIdx.x >> 7, n0 = (blockIdx.x & 127) << 6;
    if (tid < 128) {
        float s = gstat[tid], qv = gstat[128 + tid];   // complete: dispatch boundary
        float mu = s * (1.f / NB);
        float var = qv * (1.f / NB) - mu * mu;
        float istd = 1.f / __fsqrt_rn(var + EPS);
        float scale = g0[tid] * istd;
        sc[tid] = scale;
        sh[tid] = be0[tid] - mu * scale;
        chs[tid] = 0.f; chq[tid] = 0.f;
    }
    __syncthreads();
    // stage y0 tile with BN0+ReLU via in-register transpose; 2 x 64 channels
#pragma unroll
    for (int it = 0; it < 2; ++it) {
        int c = (it << 6) + l;
        const u16* src = y + (size_t)(b * CO + c) * NN + n0 + (w << 4);
        uint4 r0 = *(const uint4*)src;
        uint4 r1 = *(const uint4*)(src + 8);
        u16 raw[16];
        *(uint4*)&raw[0] = r0;
        *(uint4*)&raw[8] = r1;
        float scale = sc[c], shift = sh[c];
        int cc = c >> 3, clo = c & 7;
#pragma unroll
        for (int i = 0; i < 16; ++i) {
            int n = (w << 4) + i;
            float hv = fmaxf(b2f(raw[i]) * scale + shift, 0.f);
            xt[(n << 7) + ((cc ^ (i & 7)) << 3) + clo] = f2b(hv);
        }
    }
    __syncthreads();
    f32x4 ac0[4], ac1[4];
#pragma unroll
    for (int nf = 0; nf < 4; ++nf) {
        ac0[nf] = f32x4{0.f, 0.f, 0.f, 0.f};
        ac1[nf] = f32x4{0.f, 0.f, 0.f, 0.f};
    }
    const u16* w1r0 = W1b + (32 * w + ln) * CO + 8 * q;
    const u16* w1r1 = w1r0 + 16 * CO;
#pragma unroll
    for (int s = 0; s < 4; ++s) {
        bf16x8 a0 = *(const bf16x8*)(w1r0 + 32 * s);
        bf16x8 a1 = *(const bf16x8*)(w1r1 + 32 * s);
#pragma unroll
        for (int nf = 0; nf < 4; ++nf) {
            bf16x8 bv = *(const bf16x8*)&xt[((16 * nf + ln) << 7) + (((4 * s + q) ^ (ln & 7)) << 3)];
            ac0[nf] = __builtin_amdgcn_mfma_f32_16x16x32_bf16(a0, bv, ac0[nf], 0, 0, 0);
            ac1[nf] = __builtin_amdgcn_mfma_f32_16x16x32_bf16(a1, bv, ac1[nf], 0, 0, 0);
        }
    }
    epilogue(ac0, ac1, b1, ylds, chs, chq, w, ln, q);
    __syncthreads();
    gpart[blockIdx.x * 256 + tid] = (tid < 128) ? chs[tid] : chq[tid - 128];
    // in-place store y1pre (bf16) over the same tile of ws
    {
        int o = tid >> 1, h = tid & 1;
#pragma unroll
        for (int jj = 0; jj < 4; ++jj) {
            int j = (h << 2) + jj;
            uint4 v = *(const uint4*)&ylds[(o << 6) + ((j ^ (o & 7)) << 3)];
            *(uint4*)(y + (size_t)(b * CO + o) * NN + n0 + (j << 3)) = v;
        }
    }
}

// ---------------- final BN1 + ReLU with inline per-channel stat reduce ----------------
// each block covers exactly one channel o = (bid>>2)&127 -> reduces only that channel's
// 1024 partials (8KB, L2-resident; fixed order => deterministic, same across blocks of o)
__global__ __launch_bounds__(256) void k_bn1(
        const u16* __restrict__ y, const float* __restrict__ gpart,
        const float* __restrict__ g1, const float* __restrict__ be1,
        float* __restrict__ out) {
    __shared__ float wsum[4], wsq[4], bcast[2];
    int tid = threadIdx.x, bid = blockIdx.x;
    int o = (bid >> 2) & 127;
    float s = 0.f, q = 0.f;
#pragma unroll
    for (int j = 0; j < 4; ++j) {
        int k = tid + (j << 8);
        s += gpart[k * 256 + o];
        q += gpart[k * 256 + 128 + o];
    }
#pragma unroll
    for (int d = 1; d < 64; d <<= 1) {
        s += __shfl_xor(s, d, 64);
        q += __shfl_xor(q, d, 64);
    }
    if ((tid & 63) == 0) { wsum[tid >> 6] = s; wsq[tid >> 6] = q; }
    __syncthreads();
    if (tid == 0) {
        float st = (wsum[0] + wsum[1]) + (wsum[2] + wsum[3]);
        float qt = (wsq[0] + wsq[1]) + (wsq[2] + wsq[3]);
        float mu = st * (1.f / NB);
        float var = qt * (1.f / NB) - mu * mu;
        float istd = 1.f / __fsqrt_rn(var + EPS);
        float scale = g1[o] * istd;
        bcast[0] = scale;
        bcast[1] = be1[o] - mu * scale;
    }
    __syncthreads();
    float scale = bcast[0], shift = bcast[1];
    int t = bid * 256 + tid;
    size_t e0 = (size_t)t << 3;
    uint4 v = *(const uint4*)(y + e0);
    u16 raw[8];
    *(uint4*)raw = v;
    float r[8];
#pragma unroll
    for (int k = 0; k < 8; ++k)
        r[k] = fmaxf(b2f(raw[k]) * scale + shift, 0.f);
    *(float4*)(out + e0) = make_float4(r[0], r[1], r[2], r[3]);
    *(float4*)(out + e0 + 4) = make_float4(r[4], r[5], r[6], r[7]);
}

extern "C" void kernel_launch(void* const* d_in, const int* in_sizes, int n_in,
                              void* d_out, int out_size, void* d_ws, size_t ws_size,
                              hipStream_t stream) {
    const float* lt = (const float*)d_in[0];
    const float* lp = (const float*)d_in[1];
    const float* lf = (const float*)d_in[2];
    const float* ht = (const float*)d_in[3];
    const float* hp = (const float*)d_in[4];
    const float* hf = (const float*)d_in[5];
    const float* W0 = (const float*)d_in[6];
    const float* b0 = (const float*)d_in[7];
    const float* g0 = (const float*)d_in[8];
    const float* be0 = (const float*)d_in[9];
    const float* W1 = (const float*)d_in[10];
    const float* b1 = (const float*)d_in[11];
    const float* g1 = (const float*)d_in[12];
    const float* be1 = (const float*)d_in[13];

    char* ws = (char*)d_ws;
    u16* y0 = (u16*)ws;                         // 16.78 MB (y0, then y1pre in place)
    u16* hT = (u16*)(ws + 16777216);            // 4.19 MB
    int* idx = (int*)(ws + 20971520);           // 256 KB
    float* gstat = (float*)(ws + 21233664);     // 1 KB: L0 stats (sum, sumsq)
    u16* W0b = (u16*)(ws + 21235712);           // 48 KB
    u16* W1b = (u16*)(ws + 21284864);           // 32 KB
    float* gpart = (float*)(ws + 21317632);     // 1 MB per-block stat partials (reused)

    k_pre<<<PRE_TOTAL, 256, 0, stream>>>(lt, lp, ht, hp, hf, W0, W1, idx, hT, W0b, W1b);
    k_l0<<<1024, 256, 0, stream>>>(lf, hT, idx, W0b, b0, y0, gpart);
    k_red<<<256, 256, 0, stream>>>(gpart, gstat);
    k_l1<<<1024, 256, 0, stream>>>(y0, g0, be0, W1b, b1, gstat, gpart);
    k_bn1<<<4096, 256, 0, stream>>>(y0, gpart, g1, be1, (float*)d_out);
}

// Round 16
// 115.504 us; speedup vs baseline: 1.0078x; 1.0078x over previous
//
#include <hip/hip_runtime.h>
#include <hip/hip_bf16.h>

#define BB 8
#define NN 8192
#define MM 2048
#define C1 64
#define C2 128
#define CIN 192
#define CO 128
#define NB (BB*NN)
#define EPS 1e-5f

typedef unsigned short u16;
typedef unsigned int u32;
typedef __bf16 bf16_t;
typedef bf16_t bf16x8 __attribute__((ext_vector_type(8)));
typedef float f32x4 __attribute__((ext_vector_type(4)));
typedef float f32x2 __attribute__((ext_vector_type(2)));

static __device__ __forceinline__ float b2f(u16 u) { return __uint_as_float(((u32)u) << 16); }
static __device__ __forceinline__ u16 f2b(float f) {
    __hip_bfloat16 h = __float2bfloat16(f);
    u16 u; __builtin_memcpy(&u, &h, 2); return u;
}

// ---------------- weights f32 -> bf16 (same layout) ----------------
__global__ void k_prep_w(const float* __restrict__ W0, const float* __restrict__ W1,
                         u16* __restrict__ W0b, u16* __restrict__ W1b) {
    int t = blockIdx.x * 256 + threadIdx.x;
    if (t < CIN * CO) W0b[t] = f2b(W0[t]);
    if (t < CO * CO)  W1b[t] = f2b(W1[t]);
}

// ---------------- high_feats transpose: f32 [B][C2][M] -> bf16 [B][M][C2] ----------------
__global__ void k_prep_h(const float* __restrict__ hf, u16* __restrict__ hT) {
    __shared__ u16 s[64][65];
    int b = blockIdx.x, m0 = blockIdx.y * 64, c0 = blockIdx.z * 64;
    for (int e = threadIdx.x; e < 64 * 64; e += 256) {
        int i = e >> 6, j = e & 63;                 // i: c, j: m (coalesced in m)
        s[i][j] = f2b(hf[(b * C2 + c0 + i) * MM + m0 + j]);
    }
    __syncthreads();
    for (int e = threadIdx.x; e < 64 * 64; e += 256) {
        int ii = e & 63, jj = e >> 6;               // coalesced in c
        hT[(b * MM + m0 + jj) * C2 + c0 + ii] = s[ii][jj];
    }
}

// ---------------- nearest neighbor: Q=4 queries/thread, b128 LDS reads, pk-f32 ----------------
// One ds_read_b128 (2 candidates) serves 4 register-resident queries -> 8 pairs/DS-instr
// (R14 was 2; DS pipe was critical at ~20us, now ~5us; VALU ~14us becomes the bound).
// d2 = (x-lt)^2+(y-lp)^2 via v_pk_add/mul + scalar rn-add; bitwise == np's mul,mul,add
// (IEEE negation symmetry + rn-add commutativity). Per query: single ascending chain
// keeping LAST hit (strictly-decreasing d2) and PREV hit; sqrt-tie promotes prev
// (earlier index) == np.argmin over sqrt with first-index ties. Cross-part merge by
// (sqrt, idx) over the 8 p-lanes.
__global__ __launch_bounds__(256) void k_argmin(
        const float* __restrict__ lt_, const float* __restrict__ lp_,
        const float* __restrict__ ht_, const float* __restrict__ hp_,
        int* __restrict__ idx) {
    __shared__ float2 hs[8 * 260];                  // stride 260: 2-way bank alias (free)
    int b = blockIdx.x >> 6;                        // 64 blocks per batch
    int n0 = (blockIdx.x & 63) << 7;                // 128 queries per block
    int tid = threadIdx.x;
    for (int e = tid; e < MM; e += 256) {
        int p = e >> 8, i = e & 255;
        hs[p * 260 + i] = make_float2(ht_[b * MM + e], hp_[b * MM + e]);
    }
    __syncthreads();
    int g = tid >> 3, p = tid & 7;                  // 32 query-groups x 8 m-parts
    int qbase = n0 + (g << 2);
    f32x2 nq[4];
#pragma unroll
    for (int j = 0; j < 4; ++j) {
        nq[j][0] = -lt_[b * NN + qbase + j];
        nq[j][1] = -lp_[b * NN + qbase + j];
    }
    float dl[4]  = {1e30f, 1e30f, 1e30f, 1e30f};
    float dpv[4] = {1e30f, 1e30f, 1e30f, 1e30f};
    int il[4] = {0, 0, 0, 0}, ipx[4] = {0, 0, 0, 0};   // local indices 0..255
    const float2* hp2 = &hs[p * 260];
#pragma unroll 4
    for (int k = 0; k < 128; ++k) {                 // 2 cands/iter via ds_read_b128
        f32x4 v = *(const f32x4*)&hp2[k * 2];       // {x0,y0,x1,y1}
        f32x2 c0, c1;
        c0[0] = v[0]; c0[1] = v[1];
        c1[0] = v[2]; c1[1] = v[3];
        int i0 = k * 2;                             // uniform (SALU) -> cheap cndmask src
#pragma unroll
        for (int j = 0; j < 4; ++j) {
            f32x2 e0, e1;
            asm("v_pk_add_f32 %0, %1, %2" : "=v"(e0) : "v"(c0), "v"(nq[j]));
            asm("v_pk_mul_f32 %0, %1, %2" : "=v"(e0) : "v"(e0), "v"(e0));
            float d2a = __fadd_rn(e0[0], e0[1]);    // rn add == np fadd
            bool h0 = d2a < dl[j];                  // strict <
            dpv[j] = h0 ? dl[j] : dpv[j];
            ipx[j] = h0 ? il[j] : ipx[j];
            dl[j]  = h0 ? d2a : dl[j];
            il[j]  = h0 ? i0 : il[j];
            asm("v_pk_add_f32 %0, %1, %2" : "=v"(e1) : "v"(c1), "v"(nq[j]));
            asm("v_pk_mul_f32 %0, %1, %2" : "=v"(e1) : "v"(e1), "v"(e1));
            float d2b = __fadd_rn(e1[0], e1[1]);
            bool h1 = d2b < dl[j];
            dpv[j] = h1 ? dl[j] : dpv[j];
            ipx[j] = h1 ? il[j] : ipx[j];
            dl[j]  = h1 ? d2b : dl[j];
            il[j]  = h1 ? i0 + 1 : il[j];
        }
    }
    int mbase = p << 8;
#pragma unroll
    for (int j = 0; j < 4; ++j) {
        float sl = __fsqrt_rn(dl[j]);
        float sp = __fsqrt_rn(dpv[j]);
        int bm = mbase + ((sp == sl) ? ipx[j] : il[j]);  // sqrt-tie -> earlier hit
        float bs = sl;
#pragma unroll
        for (int d = 1; d <= 4; d <<= 1) {          // merge 8 parts (lanes g*8+p)
            float ov = __shfl_xor(bs, d, 64);
            int om = __shfl_xor(bm, d, 64);
            if (ov < bs || (ov == bs && om < bm)) { bs = ov; bm = om; }
        }
        if (p == 0) idx[b * NN + qbase + j] = bm;
    }
}

// epilogue: bias add, per-channel sum/sumsq into LDS chs/chq, bf16 store to ylds
static __device__ __forceinline__ void epilogue(
        f32x4* ac0, f32x4* ac1, const float* bias, u16* yl,
        float* chs, float* chq, int w, int ln, int q) {
#pragma unroll
    for (int mf = 0; mf < 2; ++mf) {
        f32x4* A = mf ? ac1 : ac0;
        int chb = 32 * w + 16 * mf + 4 * q;
        float bs[4], ss[4] = {0.f, 0.f, 0.f, 0.f}, sq[4] = {0.f, 0.f, 0.f, 0.f};
#pragma unroll
        for (int r = 0; r < 4; ++r) bs[r] = bias[chb + r];
#pragma unroll
        for (int nf = 0; nf < 4; ++nf) {
            int n = (nf << 4) + ln;
#pragma unroll
            for (int r = 0; r < 4; ++r) {
                float y = A[nf][r] + bs[r];
                ss[r] += y; sq[r] += y * y;
                int o = chb + r;
                yl[(o << 6) + (n ^ ((o & 7) << 3))] = f2b(y);
            }
        }
#pragma unroll
        for (int r = 0; r < 4; ++r) {
            float v = ss[r], u2 = sq[r];
#pragma unroll
            for (int d = 1; d < 16; d <<= 1) {
                v += __shfl_xor(v, d, 64);
                u2 += __shfl_xor(u2, d, 64);
            }
            if (ln == 0) { atomicAdd(&chs[chb + r], v); atomicAdd(&chq[chb + r], u2); }
        }
    }
}

// ---------------- deterministic stat reduce: gpart[1024][256] -> gout[256] ----------------
__global__ __launch_bounds__(256) void k_red(const float* __restrict__ gpart,
                                             float* __restrict__ gout) {
    __shared__ float part[4];
    int c = blockIdx.x;                    // one block per channel-slot (256)
    int t = threadIdx.x;
    float s = 0.f;
#pragma unroll
    for (int k = 0; k < 4; ++k)
        s += gpart[(t + (k << 8)) * 256 + c];
#pragma unroll
    for (int d = 1; d < 64; d <<= 1)
        s += __shfl_xor(s, d, 64);
    if ((t & 63) == 0) part[t >> 6] = s;
    __syncthreads();
    if (t == 0) gout[c] = (part[0] + part[1]) + (part[2] + part[3]);
}

// ---------------- layer 0: gather + MFMA gemm + bias -> y0 (ws, bf16) + stat partials ----------------
__global__ __launch_bounds__(256) void k_l0(
        const float* __restrict__ lf, const u16* __restrict__ hT, const int* __restrict__ idx,
        const u16* __restrict__ W0b, const float* __restrict__ b0,
        u16* __restrict__ y0, float* __restrict__ gpart) {
    __shared__ u16 xt[64 * CIN];          // B-tile [n][k] XOR-chunk-swizzled (24.5KB)
    __shared__ u16 ylds[CO * 64];         // y tile [o][n swz] (16KB)
    __shared__ float chs[CO], chq[CO];
    __shared__ int idxs[64];
    int tid = threadIdx.x;
    int l = tid & 63, w = tid >> 6, ln = l & 15, q = l >> 4;
    int b = blockIdx.x >> 7, n0 = (blockIdx.x & 127) << 6;
    if (tid < 64) idxs[tid] = idx[b * NN + n0 + tid];
    if (tid < 128) { chs[tid] = 0.f; chq[tid] = 0.f; }
    __syncthreads();
    // stage low_feats rows 0..63 via in-register transpose (lane = channel, f32 -> bf16)
    {
        const float* src = lf + (size_t)(b * C1 + l) * NN + n0 + (w << 4);
        float4 f0 = *(const float4*)src;
        float4 f1 = *(const float4*)(src + 4);
        float4 f2 = *(const float4*)(src + 8);
        float4 f3 = *(const float4*)(src + 12);
        float v[16] = {f0.x, f0.y, f0.z, f0.w, f1.x, f1.y, f1.z, f1.w,
                       f2.x, f2.y, f2.z, f2.w, f3.x, f3.y, f3.z, f3.w};
        int cc = l >> 3, clo = l & 7;
#pragma unroll
        for (int i = 0; i < 16; ++i) {
            int n = (w << 4) + i;
            xt[n * CIN + ((cc ^ (i & 7)) << 3) + clo] = f2b(v[i]);
        }
    }
    // gather nearest high rows (contiguous 256B per row from bf16 hT)
    for (int e = tid; e < 1024; e += 256) {
        int n = e >> 4, c16 = e & 15;
        uint4 v = *(const uint4*)(hT + (size_t)(b * MM + idxs[n]) * C2 + (c16 << 3));
        *(uint4*)&xt[n * CIN + (((8 + c16) ^ (n & 7)) << 3)] = v;
    }
    __syncthreads();
    f32x4 ac0[4], ac1[4];
#pragma unroll
    for (int nf = 0; nf < 4; ++nf) {
        ac0[nf] = f32x4{0.f, 0.f, 0.f, 0.f};
        ac1[nf] = f32x4{0.f, 0.f, 0.f, 0.f};
    }
    const u16* w0r0 = W0b + (32 * w + ln) * CIN + 8 * q;
    const u16* w0r1 = w0r0 + 16 * CIN;
#pragma unroll
    for (int s = 0; s < 6; ++s) {
        bf16x8 a0 = *(const bf16x8*)(w0r0 + 32 * s);
        bf16x8 a1 = *(const bf16x8*)(w0r1 + 32 * s);
#pragma unroll
        for (int nf = 0; nf < 4; ++nf) {
            bf16x8 bv = *(const bf16x8*)&xt[(16 * nf + ln) * CIN + (((4 * s + q) ^ (ln & 7)) << 3)];
            ac0[nf] = __builtin_amdgcn_mfma_f32_16x16x32_bf16(a0, bv, ac0[nf], 0, 0, 0);
            ac1[nf] = __builtin_amdgcn_mfma_f32_16x16x32_bf16(a1, bv, ac1[nf], 0, 0, 0);
        }
    }
    epilogue(ac0, ac1, b0, ylds, chs, chq, w, ln, q);
    __syncthreads();
    // per-block stat partials: unique coalesced slot, no global atomics
    gpart[blockIdx.x * 256 + tid] = (tid < 128) ? chs[tid] : chq[tid - 128];
    // coalesced store ylds -> y0 (ws, bf16)
    {
        int o = tid >> 1, h = tid & 1;
#pragma unroll
        for (int jj = 0; jj < 4; ++jj) {
            int j = (h << 2) + jj;
            uint4 v = *(const uint4*)&ylds[(o << 6) + ((j ^ (o & 7)) << 3)];
            *(uint4*)(y0 + (size_t)(b * CO + o) * NN + n0 + (j << 3)) = v;
        }
    }
}

// ---------------- layer 1: BN0+ReLU on y0 tile -> MFMA gemm -> y1pre in place + stat partials ----------------
__global__ __launch_bounds__(256) void k_l1(
        u16* __restrict__ y, const float* __restrict__ g0, const float* __restrict__ be0,
        const u16* __restrict__ W1b, const float* __restrict__ b1,
        const float* __restrict__ gstat, float* __restrict__ gpart) {
    __shared__ u16 xt[64 * CO];           // B-tile [n][k] swz (16KB)
    __shared__ u16 ylds[CO * 64];         // (16KB)
    __shared__ float chs[CO], chq[CO], sc[CO], sh[CO];
    int tid = threadIdx.x;
    int l = tid & 63, w = tid >> 6, ln = l & 15, q = l >> 4;
    int b = blockIdx.x >> 7, n0 = (blockIdx.x & 127) << 6;
    if (tid < 128) {
        float s = gstat[tid], qv = gstat[128 + tid];   // complete: dispatch boundary
        float mu = s * (1.f / NB);
        float var = qv * (1.f / NB) - mu * mu;
        float istd = 1.f / __fsqrt_rn(var + EPS);
        float scale = g0[tid] * istd;
        sc[tid] = scale;
        sh[tid] = be0[tid] - mu * scale;
        chs[tid] = 0.f; chq[tid] = 0.f;
    }
    __syncthreads();
    // stage y0 tile with BN0+ReLU via in-register transpose; 2 x 64 channels
#pragma unroll
    for (int it = 0; it < 2; ++it) {
        int c = (it << 6) + l;
        const u16* src = y + (size_t)(b * CO + c) * NN + n0 + (w << 4);
        uint4 r0 = *(const uint4*)src;
        uint4 r1 = *(const uint4*)(src + 8);
        u16 raw[16];
        *(uint4*)&raw[0] = r0;
        *(uint4*)&raw[8] = r1;
        float scale = sc[c], shift = sh[c];
        int cc = c >> 3, clo = c & 7;
#pragma unroll
        for (int i = 0; i < 16; ++i) {
            int n = (w << 4) + i;
            float hv = fmaxf(b2f(raw[i]) * scale + shift, 0.f);
            xt[(n << 7) + ((cc ^ (i & 7)) << 3) + clo] = f2b(hv);
        }
    }
    __syncthreads();
    f32x4 ac0[4], ac1[4];
#pragma unroll
    for (int nf = 0; nf < 4; ++nf) {
        ac0[nf] = f32x4{0.f, 0.f, 0.f, 0.f};
        ac1[nf] = f32x4{0.f, 0.f, 0.f, 0.f};
    }
    const u16* w1r0 = W1b + (32 * w + ln) * CO + 8 * q;
    const u16* w1r1 = w1r0 + 16 * CO;
#pragma unroll
    for (int s = 0; s < 4; ++s) {
        bf16x8 a0 = *(const bf16x8*)(w1r0 + 32 * s);
        bf16x8 a1 = *(const bf16x8*)(w1r1 + 32 * s);
#pragma unroll
        for (int nf = 0; nf < 4; ++nf) {
            bf16x8 bv = *(const bf16x8*)&xt[((16 * nf + ln) << 7) + (((4 * s + q) ^ (ln & 7)) << 3)];
            ac0[nf] = __builtin_amdgcn_mfma_f32_16x16x32_bf16(a0, bv, ac0[nf], 0, 0, 0);
            ac1[nf] = __builtin_amdgcn_mfma_f32_16x16x32_bf16(a1, bv, ac1[nf], 0, 0, 0);
        }
    }
    epilogue(ac0, ac1, b1, ylds, chs, chq, w, ln, q);
    __syncthreads();
    gpart[blockIdx.x * 256 + tid] = (tid < 128) ? chs[tid] : chq[tid - 128];
    // in-place store y1pre (bf16) over the same tile of ws
    {
        int o = tid >> 1, h = tid & 1;
#pragma unroll
        for (int jj = 0; jj < 4; ++jj) {
            int j = (h << 2) + jj;
            uint4 v = *(const uint4*)&ylds[(o << 6) + ((j ^ (o & 7)) << 3)];
            *(uint4*)(y + (size_t)(b * CO + o) * NN + n0 + (j << 3)) = v;
        }
    }
}

// ---------------- final BN1 + ReLU: y1pre (bf16, ws) -> d_out (f32) ----------------
__global__ __launch_bounds__(256) void k_bn1(
        const u16* __restrict__ y, const float* __restrict__ gstat,
        const float* __restrict__ g1, const float* __restrict__ be1,
        float* __restrict__ out) {
    int t = blockIdx.x * 256 + threadIdx.x;   // 4096 blocks: 8 elems/thread
    int o = (t >> 10) & 127;
    float s = gstat[256 + o], qv = gstat[384 + o];
    float mu = s * (1.f / NB);
    float var = qv * (1.f / NB) - mu * mu;
    float istd = 1.f / __fsqrt_rn(var + EPS);
    float scale = g1[o] * istd;
    float shift = be1[o] - mu * scale;
    size_t e0 = (size_t)t << 3;
    uint4 v = *(const uint4*)(y + e0);
    u16 raw[8];
    *(uint4*)raw = v;
    float r[8];
#pragma unroll
    for (int k = 0; k < 8; ++k)
        r[k] = fmaxf(b2f(raw[k]) * scale + shift, 0.f);
    *(float4*)(out + e0) = make_float4(r[0], r[1], r[2], r[3]);
    *(float4*)(out + e0 + 4) = make_float4(r[4], r[5], r[6], r[7]);
}

extern "C" void kernel_launch(void* const* d_in, const int* in_sizes, int n_in,
                              void* d_out, int out_size, void* d_ws, size_t ws_size,
                              hipStream_t stream) {
    const float* lt = (const float*)d_in[0];
    const float* lp = (const float*)d_in[1];
    const float* lf = (const float*)d_in[2];
    const float* ht = (const float*)d_in[3];
    const float* hp = (const float*)d_in[4];
    const float* hf = (const float*)d_in[5];
    const float* W0 = (const float*)d_in[6];
    const float* b0 = (const float*)d_in[7];
    const float* g0 = (const float*)d_in[8];
    const float* be0 = (const float*)d_in[9];
    const float* W1 = (const float*)d_in[10];
    const float* b1 = (const float*)d_in[11];
    const float* g1 = (const float*)d_in[12];
    const float* be1 = (const float*)d_in[13];

    char* ws = (char*)d_ws;
    u16* y0 = (u16*)ws;                         // 16.78 MB (y0, then y1pre in place)
    u16* hT = (u16*)(ws + 16777216);            // 4.19 MB
    int* idx = (int*)(ws + 20971520);           // 256 KB
    float* gstat = (float*)(ws + 21233664);     // 2 KB: [0:256]=L0 stats, [256:512]=L1
    u16* W0b = (u16*)(ws + 21235712);           // 48 KB
    u16* W1b = (u16*)(ws + 21284864);           // 32 KB
    float* gpart = (float*)(ws + 21317632);     // 1 MB per-block stat partials (reused)

    k_prep_w<<<96, 256, 0, stream>>>(W0, W1, W0b, W1b);
    k_prep_h<<<dim3(8, 32, 2), 256, 0, stream>>>(hf, hT);
    k_argmin<<<512, 256, 0, stream>>>(lt, lp, ht, hp, idx);
    k_l0<<<1024, 256, 0, stream>>>(lf, hT, idx, W0b, b0, y0, gpart);
    k_red<<<256, 256, 0, stream>>>(gpart, gstat);
    k_l1<<<1024, 256, 0, stream>>>(y0, g0, be0, W1b, b1, gstat, gpart);
    k_red<<<256, 256, 0, stream>>>(gpart, gstat + 256);
    k_bn1<<<4096, 256, 0, stream>>>(y0, gstat, g1, be1, (float*)d_out);
}

// Round 17
// 107.768 us; speedup vs baseline: 1.0802x; 1.0718x over previous
//
#include <hip/hip_runtime.h>
#include <hip/hip_bf16.h>

#define BB 8
#define NN 8192
#define MM 2048
#define C1 64
#define C2 128
#define CIN 192
#define CO 128
#define NB (BB*NN)
#define EPS 1e-5f

typedef unsigned short u16;
typedef unsigned int u32;
typedef __bf16 bf16_t;
typedef bf16_t bf16x8 __attribute__((ext_vector_type(8)));
typedef float f32x4 __attribute__((ext_vector_type(4)));

static __device__ __forceinline__ float b2f(u16 u) { return __uint_as_float(((u32)u) << 16); }
static __device__ __forceinline__ u16 f2b(float f) {
    __hip_bfloat16 h = __float2bfloat16(f);
    u16 u; __builtin_memcpy(&u, &h, 2); return u;
}

// ---------------- weights f32 -> bf16 (same layout) ----------------
__global__ void k_prep_w(const float* __restrict__ W0, const float* __restrict__ W1,
                         u16* __restrict__ W0b, u16* __restrict__ W1b) {
    int t = blockIdx.x * 256 + threadIdx.x;
    if (t < CIN * CO) W0b[t] = f2b(W0[t]);
    if (t < CO * CO)  W1b[t] = f2b(W1[t]);
}

// ---------------- high_feats transpose: f32 [B][C2][M] -> bf16 [B][M][C2] ----------------
__global__ void k_prep_h(const float* __restrict__ hf, u16* __restrict__ hT) {
    __shared__ u16 s[64][65];
    int b = blockIdx.x, m0 = blockIdx.y * 64, c0 = blockIdx.z * 64;
    for (int e = threadIdx.x; e < 64 * 64; e += 256) {
        int i = e >> 6, j = e & 63;                 // i: c, j: m (coalesced in m)
        s[i][j] = f2b(hf[(b * C2 + c0 + i) * MM + m0 + j]);
    }
    __syncthreads();
    for (int e = threadIdx.x; e < 64 * 64; e += 256) {
        int ii = e & 63, jj = e >> 6;               // coalesced in c
        hT[(b * MM + m0 + jj) * C2 + c0 + ii] = s[ii][jj];
    }
}

// ---------------- nearest neighbor: 16 parts x Q=2 queries/thread, b128 LDS reads ----------------
// Geometry keeps R14's TLP (2048 blocks = 8/CU) while amortizing each ds_read_b128
// (2 candidates) over 2 register-resident queries -> 4 pairs/DS-instr (R14: 2).
// DS wave-instrs drop 4x (~10us); VALU is the proven scalar 10-op/pair path (no asm,
// R16 showed pk-asm adds ~1.5x moves). d2 via rn mul,mul,add (no FMA) == np.
// Per (query, part): single ascending chain keeping LAST hit (strictly-decreasing d2)
// AND PREV hit; sqrt-tie promotes prev (earlier index) == np.argmin over sqrt with
// first-index ties. Cross-part merge by (sqrt, idx) over 16 p-lanes (lane bits 0-3).
__global__ __launch_bounds__(256) void k_argmin(
        const float* __restrict__ lt_, const float* __restrict__ lp_,
        const float* __restrict__ ht_, const float* __restrict__ hp_,
        int* __restrict__ idx) {
    __shared__ float2 hs[16 * 130];                 // stride 130: 2-way bank alias (free)
    int b = blockIdx.x >> 8;                        // 256 blocks per batch
    int n0 = (blockIdx.x & 255) << 5;               // 32 queries per block
    int tid = threadIdx.x;
    for (int e = tid; e < MM; e += 256) {
        int p = e >> 7, i = e & 127;
        hs[p * 130 + i] = make_float2(ht_[b * MM + e], hp_[b * MM + e]);
    }
    __syncthreads();
    int g = tid >> 4, p = tid & 15;                 // 16 query-groups x 16 m-parts
    int qbase = n0 + (g << 1);
    float lt0 = lt_[b * NN + qbase],     lp0 = lp_[b * NN + qbase];
    float lt1 = lt_[b * NN + qbase + 1], lp1 = lp_[b * NN + qbase + 1];
    float dl[2]  = {1e30f, 1e30f};
    float dpv[2] = {1e30f, 1e30f};
    int il[2] = {0, 0}, ipx[2] = {0, 0};            // local indices 0..127
    const float2* hp2 = &hs[p * 130];
#pragma unroll 8
    for (int k = 0; k < 64; ++k) {                  // 2 cands/iter via ds_read_b128
        f32x4 v = *(const f32x4*)&hp2[k * 2];       // {xA,yA,xB,yB}: cands 2k, 2k+1
        // ---- query 0: cand A then cand B (ascending within chain) ----
        {
            float dtA = lt0 - v[0], dpA = lp0 - v[1];
            float d2A = __fadd_rn(__fmul_rn(dtA, dtA), __fmul_rn(dpA, dpA));
            bool hA = d2A < dl[0];
            dpv[0] = hA ? dl[0] : dpv[0];
            ipx[0] = hA ? il[0] : ipx[0];
            dl[0]  = hA ? d2A : dl[0];
            il[0]  = hA ? (k * 2) : il[0];
            float dtB = lt0 - v[2], dpB = lp0 - v[3];
            float d2B = __fadd_rn(__fmul_rn(dtB, dtB), __fmul_rn(dpB, dpB));
            bool hB = d2B < dl[0];
            dpv[0] = hB ? dl[0] : dpv[0];
            ipx[0] = hB ? il[0] : ipx[0];
            dl[0]  = hB ? d2B : dl[0];
            il[0]  = hB ? (k * 2 + 1) : il[0];
        }
        // ---- query 1 ----
        {
            float dtA = lt1 - v[0], dpA = lp1 - v[1];
            float d2A = __fadd_rn(__fmul_rn(dtA, dtA), __fmul_rn(dpA, dpA));
            bool hA = d2A < dl[1];
            dpv[1] = hA ? dl[1] : dpv[1];
            ipx[1] = hA ? il[1] : ipx[1];
            dl[1]  = hA ? d2A : dl[1];
            il[1]  = hA ? (k * 2) : il[1];
            float dtB = lt1 - v[2], dpB = lp1 - v[3];
            float d2B = __fadd_rn(__fmul_rn(dtB, dtB), __fmul_rn(dpB, dpB));
            bool hB = d2B < dl[1];
            dpv[1] = hB ? dl[1] : dpv[1];
            ipx[1] = hB ? il[1] : ipx[1];
            dl[1]  = hB ? d2B : dl[1];
            il[1]  = hB ? (k * 2 + 1) : il[1];
        }
    }
    int mbase = p << 7;                             // part p covers [128p, 128p+128)
#pragma unroll
    for (int j = 0; j < 2; ++j) {
        float sl = __fsqrt_rn(dl[j]);
        float sp = __fsqrt_rn(dpv[j]);
        int bm = mbase + ((sp == sl) ? ipx[j] : il[j]);    // sqrt-tie -> earlier hit
        float bs = sl;
#pragma unroll
        for (int d = 1; d <= 8; d <<= 1) {          // merge 16 parts (lane bits 0-3)
            float ov = __shfl_xor(bs, d, 64);
            int om = __shfl_xor(bm, d, 64);
            if (ov < bs || (ov == bs && om < bm)) { bs = ov; bm = om; }
        }
        if (p == 0) idx[b * NN + qbase + j] = bm;
    }
}

// epilogue: bias add, per-channel sum/sumsq into LDS chs/chq, bf16 store to ylds
static __device__ __forceinline__ void epilogue(
        f32x4* ac0, f32x4* ac1, const float* bias, u16* yl,
        float* chs, float* chq, int w, int ln, int q) {
#pragma unroll
    for (int mf = 0; mf < 2; ++mf) {
        f32x4* A = mf ? ac1 : ac0;
        int chb = 32 * w + 16 * mf + 4 * q;
        float bs[4], ss[4] = {0.f, 0.f, 0.f, 0.f}, sq[4] = {0.f, 0.f, 0.f, 0.f};
#pragma unroll
        for (int r = 0; r < 4; ++r) bs[r] = bias[chb + r];
#pragma unroll
        for (int nf = 0; nf < 4; ++nf) {
            int n = (nf << 4) + ln;
#pragma unroll
            for (int r = 0; r < 4; ++r) {
                float y = A[nf][r] + bs[r];
                ss[r] += y; sq[r] += y * y;
                int o = chb + r;
                yl[(o << 6) + (n ^ ((o & 7) << 3))] = f2b(y);
            }
        }
#pragma unroll
        for (int r = 0; r < 4; ++r) {
            float v = ss[r], u2 = sq[r];
#pragma unroll
            for (int d = 1; d < 16; d <<= 1) {
                v += __shfl_xor(v, d, 64);
                u2 += __shfl_xor(u2, d, 64);
            }
            if (ln == 0) { atomicAdd(&chs[chb + r], v); atomicAdd(&chq[chb + r], u2); }
        }
    }
}

// ---------------- deterministic stat reduce: gpart[1024][256] -> gout[256] ----------------
__global__ __launch_bounds__(256) void k_red(const float* __restrict__ gpart,
                                             float* __restrict__ gout) {
    __shared__ float part[4];
    int c = blockIdx.x;                    // one block per channel-slot (256)
    int t = threadIdx.x;
    float s = 0.f;
#pragma unroll
    for (int k = 0; k < 4; ++k)
        s += gpart[(t + (k << 8)) * 256 + c];
#pragma unroll
    for (int d = 1; d < 64; d <<= 1)
        s += __shfl_xor(s, d, 64);
    if ((t & 63) == 0) part[t >> 6] = s;
    __syncthreads();
    if (t == 0) gout[c] = (part[0] + part[1]) + (part[2] + part[3]);
}

// ---------------- layer 0: gather + MFMA gemm + bias -> y0 (ws, bf16) + stat partials ----------------
__global__ __launch_bounds__(256) void k_l0(
        const float* __restrict__ lf, const u16* __restrict__ hT, const int* __restrict__ idx,
        const u16* __restrict__ W0b, const float* __restrict__ b0,
        u16* __restrict__ y0, float* __restrict__ gpart) {
    __shared__ u16 xt[64 * CIN];          // B-tile [n][k] XOR-chunk-swizzled (24.5KB)
    __shared__ u16 ylds[CO * 64];         // y tile [o][n swz] (16KB)
    __shared__ float chs[CO], chq[CO];
    __shared__ int idxs[64];
    int tid = threadIdx.x;
    int l = tid & 63, w = tid >> 6, ln = l & 15, q = l >> 4;
    int b = blockIdx.x >> 7, n0 = (blockIdx.x & 127) << 6;
    if (tid < 64) idxs[tid] = idx[b * NN + n0 + tid];
    if (tid < 128) { chs[tid] = 0.f; chq[tid] = 0.f; }
    __syncthreads();
    // stage low_feats rows 0..63 via in-register transpose (lane = channel, f32 -> bf16)
    {
        const float* src = lf + (size_t)(b * C1 + l) * NN + n0 + (w << 4);
        float4 f0 = *(const float4*)src;
        float4 f1 = *(const float4*)(src + 4);
        float4 f2 = *(const float4*)(src + 8);
        float4 f3 = *(const float4*)(src + 12);
        float v[16] = {f0.x, f0.y, f0.z, f0.w, f1.x, f1.y, f1.z, f1.w,
                       f2.x, f2.y, f2.z, f2.w, f3.x, f3.y, f3.z, f3.w};
        int cc = l >> 3, clo = l & 7;
#pragma unroll
        for (int i = 0; i < 16; ++i) {
            int n = (w << 4) + i;
            xt[n * CIN + ((cc ^ (i & 7)) << 3) + clo] = f2b(v[i]);
        }
    }
    // gather nearest high rows (contiguous 256B per row from bf16 hT)
    for (int e = tid; e < 1024; e += 256) {
        int n = e >> 4, c16 = e & 15;
        uint4 v = *(const uint4*)(hT + (size_t)(b * MM + idxs[n]) * C2 + (c16 << 3));
        *(uint4*)&xt[n * CIN + (((8 + c16) ^ (n & 7)) << 3)] = v;
    }
    __syncthreads();
    f32x4 ac0[4], ac1[4];
#pragma unroll
    for (int nf = 0; nf < 4; ++nf) {
        ac0[nf] = f32x4{0.f, 0.f, 0.f, 0.f};
        ac1[nf] = f32x4{0.f, 0.f, 0.f, 0.f};
    }
    const u16* w0r0 = W0b + (32 * w + ln) * CIN + 8 * q;
    const u16* w0r1 = w0r0 + 16 * CIN;
#pragma unroll
    for (int s = 0; s < 6; ++s) {
        bf16x8 a0 = *(const bf16x8*)(w0r0 + 32 * s);
        bf16x8 a1 = *(const bf16x8*)(w0r1 + 32 * s);
#pragma unroll
        for (int nf = 0; nf < 4; ++nf) {
            bf16x8 bv = *(const bf16x8*)&xt[(16 * nf + ln) * CIN + (((4 * s + q) ^ (ln & 7)) << 3)];
            ac0[nf] = __builtin_amdgcn_mfma_f32_16x16x32_bf16(a0, bv, ac0[nf], 0, 0, 0);
            ac1[nf] = __builtin_amdgcn_mfma_f32_16x16x32_bf16(a1, bv, ac1[nf], 0, 0, 0);
        }
    }
    epilogue(ac0, ac1, b0, ylds, chs, chq, w, ln, q);
    __syncthreads();
    // per-block stat partials: unique coalesced slot, no global atomics
    gpart[blockIdx.x * 256 + tid] = (tid < 128) ? chs[tid] : chq[tid - 128];
    // coalesced store ylds -> y0 (ws, bf16)
    {
        int o = tid >> 1, h = tid & 1;
#pragma unroll
        for (int jj = 0; jj < 4; ++jj) {
            int j = (h << 2) + jj;
            uint4 v = *(const uint4*)&ylds[(o << 6) + ((j ^ (o & 7)) << 3)];
            *(uint4*)(y0 + (size_t)(b * CO + o) * NN + n0 + (j << 3)) = v;
        }
    }
}

// ---------------- layer 1: BN0+ReLU on y0 tile -> MFMA gemm -> y1pre in place + stat partials ----------------
__global__ __launch_bounds__(256) void k_l1(
        u16* __restrict__ y, const float* __restrict__ g0, const float* __restrict__ be0,
        const u16* __restrict__ W1b, const float* __restrict__ b1,
        const float* __restrict__ gstat, float* __restrict__ gpart) {
    __shared__ u16 xt[64 * CO];           // B-tile [n][k] swz (16KB)
    __shared__ u16 ylds[CO * 64];         // (16KB)
    __shared__ float chs[CO], chq[CO], sc[CO], sh[CO];
    int tid = threadIdx.x;
    int l = tid & 63, w = tid >> 6, ln = l & 15, q = l >> 4;
    int b = blockIdx.x >> 7, n0 = (blockIdx.x & 127) << 6;
    if (tid < 128) {
        float s = gstat[tid], qv = gstat[128 + tid];   // complete: dispatch boundary
        float mu = s * (1.f / NB);
        float var = qv * (1.f / NB) - mu * mu;
        float istd = 1.f / __fsqrt_rn(var + EPS);
        float scale = g0[tid] * istd;
        sc[tid] = scale;
        sh[tid] = be0[tid] - mu * scale;
        chs[tid] = 0.f; chq[tid] = 0.f;
    }
    __syncthreads();
    // stage y0 tile with BN0+ReLU via in-register transpose; 2 x 64 channels
#pragma unroll
    for (int it = 0; it < 2; ++it) {
        int c = (it << 6) + l;
        const u16* src = y + (size_t)(b * CO + c) * NN + n0 + (w << 4);
        uint4 r0 = *(const uint4*)src;
        uint4 r1 = *(const uint4*)(src + 8);
        u16 raw[16];
        *(uint4*)&raw[0] = r0;
        *(uint4*)&raw[8] = r1;
        float scale = sc[c], shift = sh[c];
        int cc = c >> 3, clo = c & 7;
#pragma unroll
        for (int i = 0; i < 16; ++i) {
            int n = (w << 4) + i;
            float hv = fmaxf(b2f(raw[i]) * scale + shift, 0.f);
            xt[(n << 7) + ((cc ^ (i & 7)) << 3) + clo] = f2b(hv);
        }
    }
    __syncthreads();
    f32x4 ac0[4], ac1[4];
#pragma unroll
    for (int nf = 0; nf < 4; ++nf) {
        ac0[nf] = f32x4{0.f, 0.f, 0.f, 0.f};
        ac1[nf] = f32x4{0.f, 0.f, 0.f, 0.f};
    }
    const u16* w1r0 = W1b + (32 * w + ln) * CO + 8 * q;
    const u16* w1r1 = w1r0 + 16 * CO;
#pragma unroll
    for (int s = 0; s < 4; ++s) {
        bf16x8 a0 = *(const bf16x8*)(w1r0 + 32 * s);
        bf16x8 a1 = *(const bf16x8*)(w1r1 + 32 * s);
#pragma unroll
        for (int nf = 0; nf < 4; ++nf) {
            bf16x8 bv = *(const bf16x8*)&xt[((16 * nf + ln) << 7) + (((4 * s + q) ^ (ln & 7)) << 3)];
            ac0[nf] = __builtin_amdgcn_mfma_f32_16x16x32_bf16(a0, bv, ac0[nf], 0, 0, 0);
            ac1[nf] = __builtin_amdgcn_mfma_f32_16x16x32_bf16(a1, bv, ac1[nf], 0, 0, 0);
        }
    }
    epilogue(ac0, ac1, b1, ylds, chs, chq, w, ln, q);
    __syncthreads();
    gpart[blockIdx.x * 256 + tid] = (tid < 128) ? chs[tid] : chq[tid - 128];
    // in-place store y1pre (bf16) over the same tile of ws
    {
        int o = tid >> 1, h = tid & 1;
#pragma unroll
        for (int jj = 0; jj < 4; ++jj) {
            int j = (h << 2) + jj;
            uint4 v = *(const uint4*)&ylds[(o << 6) + ((j ^ (o & 7)) << 3)];
            *(uint4*)(y + (size_t)(b * CO + o) * NN + n0 + (j << 3)) = v;
        }
    }
}

// ---------------- final BN1 + ReLU: y1pre (bf16, ws) -> d_out (f32) ----------------
__global__ __launch_bounds__(256) void k_bn1(
        const u16* __restrict__ y, const float* __restrict__ gstat,
        const float* __restrict__ g1, const float* __restrict__ be1,
        float* __restrict__ out) {
    int t = blockIdx.x * 256 + threadIdx.x;   // 4096 blocks: 8 elems/thread
    int o = (t >> 10) & 127;
    float s = gstat[256 + o], qv = gstat[384 + o];
    float mu = s * (1.f / NB);
    float var = qv * (1.f / NB) - mu * mu;
    float istd = 1.f / __fsqrt_rn(var + EPS);
    float scale = g1[o] * istd;
    float shift = be1[o] - mu * scale;
    size_t e0 = (size_t)t << 3;
    uint4 v = *(const uint4*)(y + e0);
    u16 raw[8];
    *(uint4*)raw = v;
    float r[8];
#pragma unroll
    for (int k = 0; k < 8; ++k)
        r[k] = fmaxf(b2f(raw[k]) * scale + shift, 0.f);
    *(float4*)(out + e0) = make_float4(r[0], r[1], r[2], r[3]);
    *(float4*)(out + e0 + 4) = make_float4(r[4], r[5], r[6], r[7]);
}

extern "C" void kernel_launch(void* const* d_in, const int* in_sizes, int n_in,
                              void* d_out, int out_size, void* d_ws, size_t ws_size,
                              hipStream_t stream) {
    const float* lt = (const float*)d_in[0];
    const float* lp = (const float*)d_in[1];
    const float* lf = (const float*)d_in[2];
    const float* ht = (const float*)d_in[3];
    const float* hp = (const float*)d_in[4];
    const float* hf = (const float*)d_in[5];
    const float* W0 = (const float*)d_in[6];
    const float* b0 = (const float*)d_in[7];
    const float* g0 = (const float*)d_in[8];
    const float* be0 = (const float*)d_in[9];
    const float* W1 = (const float*)d_in[10];
    const float* b1 = (const float*)d_in[11];
    const float* g1 = (const float*)d_in[12];
    const float* be1 = (const float*)d_in[13];

    char* ws = (char*)d_ws;
    u16* y0 = (u16*)ws;                         // 16.78 MB (y0, then y1pre in place)
    u16* hT = (u16*)(ws + 16777216);            // 4.19 MB
    int* idx = (int*)(ws + 20971520);           // 256 KB
    float* gstat = (float*)(ws + 21233664);     // 2 KB: [0:256]=L0 stats, [256:512]=L1
    u16* W0b = (u16*)(ws + 21235712);           // 48 KB
    u16* W1b = (u16*)(ws + 21284864);           // 32 KB
    float* gpart = (float*)(ws + 21317632);     // 1 MB per-block stat partials (reused)

    k_prep_w<<<96, 256, 0, stream>>>(W0, W1, W0b, W1b);
    k_prep_h<<<dim3(8, 32, 2), 256, 0, stream>>>(hf, hT);
    k_argmin<<<2048, 256, 0, stream>>>(lt, lp, ht, hp, idx);
    k_l0<<<1024, 256, 0, stream>>>(lf, hT, idx, W0b, b0, y0, gpart);
    k_red<<<256, 256, 0, stream>>>(gpart, gstat);
    k_l1<<<1024, 256, 0, stream>>>(y0, g0, be0, W1b, b1, gstat, gpart);
    k_red<<<256, 256, 0, stream>>>(gpart, gstat + 256);
    k_bn1<<<4096, 256, 0, stream>>>(y0, gstat, g1, be1, (float*)d_out);
}

// Round 18
// 96.373 us; speedup vs baseline: 1.2079x; 1.1182x over previous
//
#include <hip/hip_runtime.h>
#include <hip/hip_bf16.h>

#define BB 8
#define NN 8192
#define MM 2048
#define C1 64
#define C2 128
#define CIN 192
#define CO 128
#define NB (BB*NN)
#define EPS 1e-5f

typedef unsigned short u16;
typedef unsigned int u32;
typedef unsigned long long u64;
typedef __bf16 bf16_t;
typedef bf16_t bf16x8 __attribute__((ext_vector_type(8)));
typedef float f32x4 __attribute__((ext_vector_type(4)));

static __device__ __forceinline__ float b2f(u16 u) { return __uint_as_float(((u32)u) << 16); }
static __device__ __forceinline__ u16 f2b(float f) {
    __hip_bfloat16 h = __float2bfloat16(f);
    u16 u; __builtin_memcpy(&u, &h, 2); return u;
}

// ---------------- weights f32 -> bf16 (same layout) ----------------
__global__ void k_prep_w(const float* __restrict__ W0, const float* __restrict__ W1,
                         u16* __restrict__ W0b, u16* __restrict__ W1b) {
    int t = blockIdx.x * 256 + threadIdx.x;
    if (t < CIN * CO) W0b[t] = f2b(W0[t]);
    if (t < CO * CO)  W1b[t] = f2b(W1[t]);
}

// ---------------- high_feats transpose: f32 [B][C2][M] -> bf16 [B][M][C2] ----------------
__global__ void k_prep_h(const float* __restrict__ hf, u16* __restrict__ hT) {
    __shared__ u16 s[64][65];
    int b = blockIdx.x, m0 = blockIdx.y * 64, c0 = blockIdx.z * 64;
    for (int e = threadIdx.x; e < 64 * 64; e += 256) {
        int i = e >> 6, j = e & 63;                 // i: c, j: m (coalesced in m)
        s[i][j] = f2b(hf[(b * C2 + c0 + i) * MM + m0 + j]);
    }
    __syncthreads();
    for (int e = threadIdx.x; e < 64 * 64; e += 256) {
        int ii = e & 63, jj = e >> 6;               // coalesced in c
        hT[(b * MM + m0 + jj) * C2 + c0 + ii] = s[ii][jj];
    }
}

// ---------------- nearest neighbor: 2-phase exact argmin ----------------
// Phase 1: per (query, part) pure v_min_f32 over d2 (6 VALU/pair, no index
// bookkeeping) -- valid because sqrt_rn is monotone: min_i sqrt(d2_i) =
// sqrt_rn(min_i d2_i). Two independent even/odd chains kill the serial dep.
// Phase 2 (exact np first-index): s_min = min over parts of sqrt_rn(m2_p);
// the FIRST part p* with sqrt_rn(m2_p)==s_min contains the np argmin (any
// tying candidate's part satisfies m2 <= m2_p <= d2_cand => sqrt(m2_p)==s_min,
// and earlier parts have sqrt(m2_p) > s_min => no tying candidate). 16 lanes
// cooperatively rescan part p* (8 cands/lane, bank-rotated, order-independent
// first-index via min(pred ? local_idx : INF)). d2 via rn mul,mul,add == np.
__global__ __launch_bounds__(256) void k_argmin(
        const float* __restrict__ lt_, const float* __restrict__ lp_,
        const float* __restrict__ ht_, const float* __restrict__ hp_,
        int* __restrict__ idx) {
    __shared__ float2 hs[16 * 130];                 // stride 130: 2-way bank alias (free)
    int b = blockIdx.x >> 8;                        // 256 blocks per batch
    int n0 = (blockIdx.x & 255) << 5;               // 32 queries per block
    int tid = threadIdx.x;
    for (int e = tid; e < MM; e += 256) {
        int p = e >> 7, i = e & 127;
        hs[p * 130 + i] = make_float2(ht_[b * MM + e], hp_[b * MM + e]);
    }
    __syncthreads();
    int g = tid >> 4, p = tid & 15;                 // 16 query-groups x 16 m-parts
    int gw = (tid & 63) >> 4;                       // group within wave (for ballot)
    int qbase = n0 + (g << 1);
    float lt0 = lt_[b * NN + qbase],     lp0 = lp_[b * NN + qbase];
    float lt1 = lt_[b * NN + qbase + 1], lp1 = lp_[b * NN + qbase + 1];
    const float2* hp2 = &hs[p * 130];
    // ---- phase 1: pure min over this part's 128 candidates ----
    float me0 = 1e30f, mo0 = 1e30f, me1 = 1e30f, mo1 = 1e30f;
#pragma unroll 8
    for (int k = 0; k < 64; ++k) {                  // 2 cands/iter via ds_read_b128
        f32x4 v = *(const f32x4*)&hp2[k * 2];       // {xA,yA,xB,yB}
        float dtA0 = lt0 - v[0], dpA0 = lp0 - v[1];
        me0 = fminf(me0, __fadd_rn(__fmul_rn(dtA0, dtA0), __fmul_rn(dpA0, dpA0)));
        float dtB0 = lt0 - v[2], dpB0 = lp0 - v[3];
        mo0 = fminf(mo0, __fadd_rn(__fmul_rn(dtB0, dtB0), __fmul_rn(dpB0, dpB0)));
        float dtA1 = lt1 - v[0], dpA1 = lp1 - v[1];
        me1 = fminf(me1, __fadd_rn(__fmul_rn(dtA1, dtA1), __fmul_rn(dpA1, dpA1)));
        float dtB1 = lt1 - v[2], dpB1 = lp1 - v[3];
        mo1 = fminf(mo1, __fadd_rn(__fmul_rn(dtB1, dtB1), __fmul_rn(dpB1, dpB1)));
    }
    float sp0 = __fsqrt_rn(fminf(me0, mo0));        // this part's min sqrt (q0)
    float sp1 = __fsqrt_rn(fminf(me1, mo1));        // (q1)
    // ---- merge s_min over 16 parts (lane bits 0-3) ----
    float s0 = sp0, s1 = sp1;
#pragma unroll
    for (int d = 1; d <= 8; d <<= 1) {
        s0 = fminf(s0, __shfl_xor(s0, d, 64));
        s1 = fminf(s1, __shfl_xor(s1, d, 64));
    }
    // ---- find first tying part per query ----
    u64 bm0 = __ballot(sp0 == s0);
    u64 bm1 = __ballot(sp1 == s1);
    int P0 = __ffs((int)((bm0 >> (gw * 16)) & 0xffffULL)) - 1;
    int P1 = __ffs((int)((bm1 >> (gw * 16)) & 0xffffULL)) - 1;
    // ---- phase 2: cooperative rescan of part P0/P1 (8 cands per lane) ----
    int f0 = 0x7fffffff, f1 = 0x7fffffff;
    const float2* r0 = &hs[P0 * 130 + (p << 3)];
    const float2* r1 = &hs[P1 * 130 + (p << 3)];
#pragma unroll
    for (int k = 0; k < 4; ++k) {
        int kk = (k + p) & 3;                       // bank-rotated; order-independent
        {
            f32x4 v = *(const f32x4*)&r0[kk * 2];
            int lc = (p << 3) + (kk << 1);
            float dtA = lt0 - v[0], dpA = lp0 - v[1];
            float sA = __fsqrt_rn(__fadd_rn(__fmul_rn(dtA, dtA), __fmul_rn(dpA, dpA)));
            f0 = min(f0, (sA == s0) ? lc : 0x7fffffff);
            float dtB = lt0 - v[2], dpB = lp0 - v[3];
            float sB = __fsqrt_rn(__fadd_rn(__fmul_rn(dtB, dtB), __fmul_rn(dpB, dpB)));
            f0 = min(f0, (sB == s0) ? lc + 1 : 0x7fffffff);
        }
        {
            f32x4 v = *(const f32x4*)&r1[kk * 2];
            int lc = (p << 3) + (kk << 1);
            float dtA = lt1 - v[0], dpA = lp1 - v[1];
            float sA = __fsqrt_rn(__fadd_rn(__fmul_rn(dtA, dtA), __fmul_rn(dpA, dpA)));
            f1 = min(f1, (sA == s1) ? lc : 0x7fffffff);
            float dtB = lt1 - v[2], dpB = lp1 - v[3];
            float sB = __fsqrt_rn(__fadd_rn(__fmul_rn(dtB, dtB), __fmul_rn(dpB, dpB)));
            f1 = min(f1, (sB == s1) ? lc + 1 : 0x7fffffff);
        }
    }
#pragma unroll
    for (int d = 1; d <= 8; d <<= 1) {              // first tying local idx over lanes
        f0 = min(f0, __shfl_xor(f0, d, 64));
        f1 = min(f1, __shfl_xor(f1, d, 64));
    }
    if (p == 0) {
        idx[b * NN + qbase]     = (P0 << 7) + f0;
        idx[b * NN + qbase + 1] = (P1 << 7) + f1;
    }
}

// epilogue: bias add, per-channel sum/sumsq into LDS chs/chq, bf16 store to ylds
static __device__ __forceinline__ void epilogue(
        f32x4* ac0, f32x4* ac1, const float* bias, u16* yl,
        float* chs, float* chq, int w, int ln, int q) {
#pragma unroll
    for (int mf = 0; mf < 2; ++mf) {
        f32x4* A = mf ? ac1 : ac0;
        int chb = 32 * w + 16 * mf + 4 * q;
        float bs[4], ss[4] = {0.f, 0.f, 0.f, 0.f}, sq[4] = {0.f, 0.f, 0.f, 0.f};
#pragma unroll
        for (int r = 0; r < 4; ++r) bs[r] = bias[chb + r];
#pragma unroll
        for (int nf = 0; nf < 4; ++nf) {
            int n = (nf << 4) + ln;
#pragma unroll
            for (int r = 0; r < 4; ++r) {
                float y = A[nf][r] + bs[r];
                ss[r] += y; sq[r] += y * y;
                int o = chb + r;
                yl[(o << 6) + (n ^ ((o & 7) << 3))] = f2b(y);
            }
        }
#pragma unroll
        for (int r = 0; r < 4; ++r) {
            float v = ss[r], u2 = sq[r];
#pragma unroll
            for (int d = 1; d < 16; d <<= 1) {
                v += __shfl_xor(v, d, 64);
                u2 += __shfl_xor(u2, d, 64);
            }
            if (ln == 0) { atomicAdd(&chs[chb + r], v); atomicAdd(&chq[chb + r], u2); }
        }
    }
}

// ---------------- deterministic stat reduce: gpart[1024][256] -> gout[256] ----------------
__global__ __launch_bounds__(256) void k_red(const float* __restrict__ gpart,
                                             float* __restrict__ gout) {
    __shared__ float part[4];
    int c = blockIdx.x;                    // one block per channel-slot (256)
    int t = threadIdx.x;
    float s = 0.f;
#pragma unroll
    for (int k = 0; k < 4; ++k)
        s += gpart[(t + (k << 8)) * 256 + c];
#pragma unroll
    for (int d = 1; d < 64; d <<= 1)
        s += __shfl_xor(s, d, 64);
    if ((t & 63) == 0) part[t >> 6] = s;
    __syncthreads();
    if (t == 0) gout[c] = (part[0] + part[1]) + (part[2] + part[3]);
}

// ---------------- layer 0: gather + MFMA gemm + bias -> y0 (ws, bf16) + stat partials ----------------
__global__ __launch_bounds__(256) void k_l0(
        const float* __restrict__ lf, const u16* __restrict__ hT, const int* __restrict__ idx,
        const u16* __restrict__ W0b, const float* __restrict__ b0,
        u16* __restrict__ y0, float* __restrict__ gpart) {
    __shared__ u16 xt[64 * CIN];          // B-tile [n][k] XOR-chunk-swizzled (24.5KB)
    __shared__ u16 ylds[CO * 64];         // y tile [o][n swz] (16KB)
    __shared__ float chs[CO], chq[CO];
    __shared__ int idxs[64];
    int tid = threadIdx.x;
    int l = tid & 63, w = tid >> 6, ln = l & 15, q = l >> 4;
    int b = blockIdx.x >> 7, n0 = (blockIdx.x & 127) << 6;
    if (tid < 64) idxs[tid] = idx[b * NN + n0 + tid];
    if (tid < 128) { chs[tid] = 0.f; chq[tid] = 0.f; }
    __syncthreads();
    // stage low_feats rows 0..63 via in-register transpose (lane = channel, f32 -> bf16)
    {
        const float* src = lf + (size_t)(b * C1 + l) * NN + n0 + (w << 4);
        float4 f0 = *(const float4*)src;
        float4 f1 = *(const float4*)(src + 4);
        float4 f2 = *(const float4*)(src + 8);
        float4 f3 = *(const float4*)(src + 12);
        float v[16] = {f0.x, f0.y, f0.z, f0.w, f1.x, f1.y, f1.z, f1.w,
                       f2.x, f2.y, f2.z, f2.w, f3.x, f3.y, f3.z, f3.w};
        int cc = l >> 3, clo = l & 7;
#pragma unroll
        for (int i = 0; i < 16; ++i) {
            int n = (w << 4) + i;
            xt[n * CIN + ((cc ^ (i & 7)) << 3) + clo] = f2b(v[i]);
        }
    }
    // gather nearest high rows (contiguous 256B per row from bf16 hT)
    for (int e = tid; e < 1024; e += 256) {
        int n = e >> 4, c16 = e & 15;
        uint4 v = *(const uint4*)(hT + (size_t)(b * MM + idxs[n]) * C2 + (c16 << 3));
        *(uint4*)&xt[n * CIN + (((8 + c16) ^ (n & 7)) << 3)] = v;
    }
    __syncthreads();
    f32x4 ac0[4], ac1[4];
#pragma unroll
    for (int nf = 0; nf < 4; ++nf) {
        ac0[nf] = f32x4{0.f, 0.f, 0.f, 0.f};
        ac1[nf] = f32x4{0.f, 0.f, 0.f, 0.f};
    }
    const u16* w0r0 = W0b + (32 * w + ln) * CIN + 8 * q;
    const u16* w0r1 = w0r0 + 16 * CIN;
#pragma unroll
    for (int s = 0; s < 6; ++s) {
        bf16x8 a0 = *(const bf16x8*)(w0r0 + 32 * s);
        bf16x8 a1 = *(const bf16x8*)(w0r1 + 32 * s);
#pragma unroll
        for (int nf = 0; nf < 4; ++nf) {
            bf16x8 bv = *(const bf16x8*)&xt[(16 * nf + ln) * CIN + (((4 * s + q) ^ (ln & 7)) << 3)];
            ac0[nf] = __builtin_amdgcn_mfma_f32_16x16x32_bf16(a0, bv, ac0[nf], 0, 0, 0);
            ac1[nf] = __builtin_amdgcn_mfma_f32_16x16x32_bf16(a1, bv, ac1[nf], 0, 0, 0);
        }
    }
    epilogue(ac0, ac1, b0, ylds, chs, chq, w, ln, q);
    __syncthreads();
    // per-block stat partials: unique coalesced slot, no global atomics
    gpart[blockIdx.x * 256 + tid] = (tid < 128) ? chs[tid] : chq[tid - 128];
    // coalesced store ylds -> y0 (ws, bf16)
    {
        int o = tid >> 1, h = tid & 1;
#pragma unroll
        for (int jj = 0; jj < 4; ++jj) {
            int j = (h << 2) + jj;
            uint4 v = *(const uint4*)&ylds[(o << 6) + ((j ^ (o & 7)) << 3)];
            *(uint4*)(y0 + (size_t)(b * CO + o) * NN + n0 + (j << 3)) = v;
        }
    }
}

// ---------------- layer 1: BN0+ReLU on y0 tile -> MFMA gemm -> y1pre in place + stat partials ----------------
__global__ __launch_bounds__(256) void k_l1(
        u16* __restrict__ y, const float* __restrict__ g0, const float* __restrict__ be0,
        const u16* __restrict__ W1b, const float* __restrict__ b1,
        const float* __restrict__ gstat, float* __restrict__ gpart) {
    __shared__ u16 xt[64 * CO];           // B-tile [n][k] swz (16KB)
    __shared__ u16 ylds[CO * 64];         // (16KB)
    __shared__ float chs[CO], chq[CO], sc[CO], sh[CO];
    int tid = threadIdx.x;
    int l = tid & 63, w = tid >> 6, ln = l & 15, q = l >> 4;
    int b = blockIdx.x >> 7, n0 = (blockIdx.x & 127) << 6;
    if (tid < 128) {
        float s = gstat[tid], qv = gstat[128 + tid];   // complete: dispatch boundary
        float mu = s * (1.f / NB);
        float var = qv * (1.f / NB) - mu * mu;
        float istd = 1.f / __fsqrt_rn(var + EPS);
        float scale = g0[tid] * istd;
        sc[tid] = scale;
        sh[tid] = be0[tid] - mu * scale;
        chs[tid] = 0.f; chq[tid] = 0.f;
    }
    __syncthreads();
    // stage y0 tile with BN0+ReLU via in-register transpose; 2 x 64 channels
#pragma unroll
    for (int it = 0; it < 2; ++it) {
        int c = (it << 6) + l;
        const u16* src = y + (size_t)(b * CO + c) * NN + n0 + (w << 4);
        uint4 r0 = *(const uint4*)src;
        uint4 r1 = *(const uint4*)(src + 8);
        u16 raw[16];
        *(uint4*)&raw[0] = r0;
        *(uint4*)&raw[8] = r1;
        float scale = sc[c], shift = sh[c];
        int cc = c >> 3, clo = c & 7;
#pragma unroll
        for (int i = 0; i < 16; ++i) {
            int n = (w << 4) + i;
            float hv = fmaxf(b2f(raw[i]) * scale + shift, 0.f);
            xt[(n << 7) + ((cc ^ (i & 7)) << 3) + clo] = f2b(hv);
        }
    }
    __syncthreads();
    f32x4 ac0[4], ac1[4];
#pragma unroll
    for (int nf = 0; nf < 4; ++nf) {
        ac0[nf] = f32x4{0.f, 0.f, 0.f, 0.f};
        ac1[nf] = f32x4{0.f, 0.f, 0.f, 0.f};
    }
    const u16* w1r0 = W1b + (32 * w + ln) * CO + 8 * q;
    const u16* w1r1 = w1r0 + 16 * CO;
#pragma unroll
    for (int s = 0; s < 4; ++s) {
        bf16x8 a0 = *(const bf16x8*)(w1r0 + 32 * s);
        bf16x8 a1 = *(const bf16x8*)(w1r1 + 32 * s);
#pragma unroll
        for (int nf = 0; nf < 4; ++nf) {
            bf16x8 bv = *(const bf16x8*)&xt[((16 * nf + ln) << 7) + (((4 * s + q) ^ (ln & 7)) << 3)];
            ac0[nf] = __builtin_amdgcn_mfma_f32_16x16x32_bf16(a0, bv, ac0[nf], 0, 0, 0);
            ac1[nf] = __builtin_amdgcn_mfma_f32_16x16x32_bf16(a1, bv, ac1[nf], 0, 0, 0);
        }
    }
    epilogue(ac0, ac1, b1, ylds, chs, chq, w, ln, q);
    __syncthreads();
    gpart[blockIdx.x * 256 + tid] = (tid < 128) ? chs[tid] : chq[tid - 128];
    // in-place store y1pre (bf16) over the same tile of ws
    {
        int o = tid >> 1, h = tid & 1;
#pragma unroll
        for (int jj = 0; jj < 4; ++jj) {
            int j = (h << 2) + jj;
            uint4 v = *(const uint4*)&ylds[(o << 6) + ((j ^ (o & 7)) << 3)];
            *(uint4*)(y + (size_t)(b * CO + o) * NN + n0 + (j << 3)) = v;
        }
    }
}

// ---------------- final BN1 + ReLU: y1pre (bf16, ws) -> d_out (f32) ----------------
__global__ __launch_bounds__(256) void k_bn1(
        const u16* __restrict__ y, const float* __restrict__ gstat,
        const float* __restrict__ g1, const float* __restrict__ be1,
        float* __restrict__ out) {
    int t = blockIdx.x * 256 + threadIdx.x;   // 4096 blocks: 8 elems/thread
    int o = (t >> 10) & 127;
    float s = gstat[256 + o], qv = gstat[384 + o];
    float mu = s * (1.f / NB);
    float var = qv * (1.f / NB) - mu * mu;
    float istd = 1.f / __fsqrt_rn(var + EPS);
    float scale = g1[o] * istd;
    float shift = be1[o] - mu * scale;
    size_t e0 = (size_t)t << 3;
    uint4 v = *(const uint4*)(y + e0);
    u16 raw[8];
    *(uint4*)raw = v;
    float r[8];
#pragma unroll
    for (int k = 0; k < 8; ++k)
        r[k] = fmaxf(b2f(raw[k]) * scale + shift, 0.f);
    *(float4*)(out + e0) = make_float4(r[0], r[1], r[2], r[3]);
    *(float4*)(out + e0 + 4) = make_float4(r[4], r[5], r[6], r[7]);
}

extern "C" void kernel_launch(void* const* d_in, const int* in_sizes, int n_in,
                              void* d_out, int out_size, void* d_ws, size_t ws_size,
                              hipStream_t stream) {
    const float* lt = (const float*)d_in[0];
    const float* lp = (const float*)d_in[1];
    const float* lf = (const float*)d_in[2];
    const float* ht = (const float*)d_in[3];
    const float* hp = (const float*)d_in[4];
    const float* hf = (const float*)d_in[5];
    const float* W0 = (const float*)d_in[6];
    const float* b0 = (const float*)d_in[7];
    const float* g0 = (const float*)d_in[8];
    const float* be0 = (const float*)d_in[9];
    const float* W1 = (const float*)d_in[10];
    const float* b1 = (const float*)d_in[11];
    const float* g1 = (const float*)d_in[12];
    const float* be1 = (const float*)d_in[13];

    char* ws = (char*)d_ws;
    u16* y0 = (u16*)ws;                         // 16.78 MB (y0, then y1pre in place)
    u16* hT = (u16*)(ws + 16777216);            // 4.19 MB
    int* idx = (int*)(ws + 20971520);           // 256 KB
    float* gstat = (float*)(ws + 21233664);     // 2 KB: [0:256]=L0 stats, [256:512]=L1
    u16* W0b = (u16*)(ws + 21235712);           // 48 KB
    u16* W1b = (u16*)(ws + 21284864);           // 32 KB
    float* gpart = (float*)(ws + 21317632);     // 1 MB per-block stat partials (reused)

    k_prep_w<<<96, 256, 0, stream>>>(W0, W1, W0b, W1b);
    k_prep_h<<<dim3(8, 32, 2), 256, 0, stream>>>(hf, hT);
    k_argmin<<<2048, 256, 0, stream>>>(lt, lp, ht, hp, idx);
    k_l0<<<1024, 256, 0, stream>>>(lf, hT, idx, W0b, b0, y0, gpart);
    k_red<<<256, 256, 0, stream>>>(gpart, gstat);
    k_l1<<<1024, 256, 0, stream>>>(y0, g0, be0, W1b, b1, gstat, gpart);
    k_red<<<256, 256, 0, stream>>>(gpart, gstat + 256);
    k_bn1<<<4096, 256, 0, stream>>>(y0, gstat, g1, be1, (float*)d_out);
}